// Round 5
// baseline (300.574 us; speedup 1.0000x reference)
//
#include <hip/hip_runtime.h>
#include <cstdint>

#define DEV __device__ __forceinline__

typedef __bf16 bf16x4 __attribute__((ext_vector_type(4)));
typedef __bf16 bf16x8 __attribute__((ext_vector_type(8)));
typedef float  floatx4 __attribute__((ext_vector_type(4)));
typedef short  short4v __attribute__((ext_vector_type(4)));

constexpr int BB = 8, NSEQ = 1024, DMODEL = 768, NH = 12, HD = 64;
constexpr int MTOK = BB * NSEQ;   // 8192 tokens
constexpr int NQKV = 3 * DMODEL;  // 2304
constexpr float CS = 0.18033688011112042f;  // (1/sqrt(64)) * log2(e), folded into Q

DEV void async_copy16(void* lds, const void* g) {
    // global -> LDS direct copy, 16B/lane. LDS dest must be wave-base + lane*16.
    __builtin_amdgcn_global_load_lds(
        (__attribute__((address_space(1))) void*)(const_cast<void*>(g)),
        (__attribute__((address_space(3))) void*)lds,
        16, 0, 0);
}

DEV floatx4 mfma16x32(bf16x8 a, bf16x8 b, floatx4 c) {
    return __builtin_amdgcn_mfma_f32_16x16x32_bf16(a, b, c, 0, 0, 0);
}
DEV floatx4 mfma16x16(bf16x4 a, bf16x4 b, floatx4 c) {
    // K=16 bf16 MFMA: operand k = quad*4+j  == S^T C/D row layout (key=quad*4+r)
    return __builtin_amdgcn_mfma_f32_16x16x16bf16_1k(
        __builtin_bit_cast(short4v, a), __builtin_bit_cast(short4v, b), c, 0, 0, 0);
}

// ---------------- x fp32 -> bf16 ----------------
__global__ __launch_bounds__(256) void k_convert_x(const float* __restrict__ x,
                                                   __bf16* __restrict__ xb) {
    int i = (blockIdx.x * 256 + threadIdx.x) * 4;  // grid sized exactly
    float4 v = *(const float4*)(x + i);
    bf16x4 o;
    o[0] = (__bf16)v.x; o[1] = (__bf16)v.y; o[2] = (__bf16)v.z; o[3] = (__bf16)v.w;
    *(bf16x4*)(xb + i) = o;
}

// ---------------- bias concat (q|k|v) fp32 ----------------
__global__ __launch_bounds__(256) void k_bias(const float* __restrict__ bq,
                                              const float* __restrict__ bk,
                                              const float* __restrict__ bv,
                                              float* __restrict__ out) {
    int i = blockIdx.x * 256 + threadIdx.x;  // grid = 9 -> 2304 exact
    if (i < 768) out[i] = bq[i];
    else if (i < 1536) out[i] = bk[i - 768];
    else if (i < 2304) out[i] = bv[i - 1536];
}

// ---------------- W [K,N] fp32 -> Wt [N,K] bf16 (z: 0=q 1=k 2=v 3=o) ----------------
__global__ __launch_bounds__(256) void k_transpose_w(const float* __restrict__ Wq,
                                                     const float* __restrict__ Wk,
                                                     const float* __restrict__ Wv,
                                                     const float* __restrict__ Wo,
                                                     __bf16* __restrict__ wtqkv,
                                                     __bf16* __restrict__ wto) {
    __shared__ float tile[32][33];
    int z = blockIdx.z;
    const float* W = (z == 0) ? Wq : (z == 1) ? Wk : (z == 2) ? Wv : Wo;
    int k0 = blockIdx.x * 32, n0 = blockIdx.y * 32;
    int tx = threadIdx.x & 31, ty = threadIdx.x >> 5;
#pragma unroll
    for (int p = 0; p < 4; p++)
        tile[ty + 8 * p][tx] = W[(size_t)(k0 + ty + 8 * p) * 768 + n0 + tx];
    __syncthreads();
    __bf16* out = (z < 3) ? (wtqkv + (size_t)z * 768 * 768) : wto;
#pragma unroll
    for (int p = 0; p < 4; p++)
        out[(size_t)(n0 + ty + 8 * p) * 768 + k0 + tx] = (__bf16)tile[tx][ty + 8 * p];
}

// ---------------- GEMM: C[M,Nn] = A[M,768] @ Bt[Nn,768]^T + bias ----------------
// BM=BN=128, BK=64, 4 waves each 64x64 (4x4 acc of 16x16x32 MFMA).
// QKV=true: scale Q cols by CS; route V cols (>=1536) transposed into vtb[b,h,hd,tok].
template <typename OutT, bool QKV>
__global__ __launch_bounds__(256) void k_gemm(const __bf16* __restrict__ A,
                                              const __bf16* __restrict__ Bt,
                                              const float* __restrict__ bias,
                                              OutT* __restrict__ C, int Nn,
                                              __bf16* __restrict__ vtb) {
    __shared__ __align__(16) __bf16 As[128 * 64];
    __shared__ __align__(16) __bf16 Bs[128 * 64];
    int t = threadIdx.x, lane = t & 63, w = t >> 6;
    int quad = lane >> 4, n16 = lane & 15;
    int wm = w & 1, wn = w >> 1;
    int m0 = blockIdx.x * 128, n0 = blockIdx.y * 128;
    floatx4 acc[4][4] = {};

    for (int k0 = 0; k0 < 768; k0 += 64) {
        __syncthreads();
#pragma unroll
        for (int i = 0; i < 4; i++) {  // stage A tile 128x64 (16KB)
            int off = t + i * 256;
            int row = off >> 3, pc = off & 7;
            int c = pc ^ (row & 7);
            async_copy16(&As[row * 64 + pc * 8],
                         &A[(size_t)(m0 + row) * 768 + k0 + c * 8]);
        }
#pragma unroll
        for (int i = 0; i < 4; i++) {  // stage B tile 128x64
            int off = t + i * 256;
            int row = off >> 3, pc = off & 7;
            int c = pc ^ (row & 7);
            async_copy16(&Bs[row * 64 + pc * 8],
                         &Bt[(size_t)(n0 + row) * 768 + k0 + c * 8]);
        }
        __builtin_amdgcn_s_waitcnt(0);  // drain global_load_lds before barrier
        __syncthreads();
#pragma unroll
        for (int kfi = 0; kfi < 2; kfi++) {
            bf16x8 a[4], bfr[4];
#pragma unroll
            for (int rt = 0; rt < 4; rt++) {
                int row = wm * 64 + rt * 16 + n16;
                a[rt] = *(const bf16x8*)&As[row * 64 + ((quad + 4 * kfi) ^ (row & 7)) * 8];
            }
#pragma unroll
            for (int ct = 0; ct < 4; ct++) {
                int row = wn * 64 + ct * 16 + n16;
                bfr[ct] = *(const bf16x8*)&Bs[row * 64 + ((quad + 4 * kfi) ^ (row & 7)) * 8];
            }
#pragma unroll
            for (int rt = 0; rt < 4; rt++)
#pragma unroll
                for (int ct = 0; ct < 4; ct++)
                    acc[rt][ct] = mfma16x32(a[rt], bfr[ct], acc[rt][ct]);
        }
    }
    // epilogue: C/D layout col=lane&15, row=quad*4+reg
#pragma unroll
    for (int ct = 0; ct < 4; ct++) {
        int col = n0 + wn * 64 + ct * 16 + n16;
        float bs = bias[col];
        if (QKV && col >= 1536) {
            // V region -> vtb[b,h,hd,tok], 4 consecutive tokens per b64 store
            int vcol = col - 1536;
            int hh = vcol >> 6, hd = vcol & 63;
#pragma unroll
            for (int rt = 0; rt < 4; rt++) {
                int row0 = m0 + wm * 64 + rt * 16 + quad * 4;
                int bb = row0 >> 10, tok = row0 & 1023;
                bf16x4 pkk;
#pragma unroll
                for (int r = 0; r < 4; r++) pkk[r] = (__bf16)(acc[rt][ct][r] + bs);
                *(bf16x4*)&vtb[((size_t)(bb * NH + hh) * 64 + hd) * 1024 + tok] = pkk;
            }
        } else {
            float mult = (QKV && col < 768) ? CS : 1.0f;
#pragma unroll
            for (int rt = 0; rt < 4; rt++) {
#pragma unroll
                for (int r = 0; r < 4; r++) {
                    int row = m0 + wm * 64 + rt * 16 + quad * 4 + r;
                    C[(size_t)row * Nn + col] = (OutT)((acc[rt][ct][r] + bs) * mult);
                }
            }
        }
    }
}

// ---------------- flash attention: barrier-free, LDS-free main loop ----------------
// Block = 32 qrows of one (b,h); wave w owns keys [kt*64+w*16, +16) each iter.
// No K/V reuse across waves exists in this partition, so K and V fragments load
// DIRECTLY global->VGPR (L2-resident via XCD pinning): no LDS staging, no
// barriers in the loop -> waves pipeline independently, compiler prefetches
// across iterations via vmcnt scheduling.
// S^T = K_sub·Q^T (16x16x32): C/D row = quad*4+r = key == K=16 MFMA operand k,
// so P feeds PV register-direct. Quiet softmax: out = p/(max(p)+sum(p)), p=2^s.
__global__ __launch_bounds__(256) void k_attn(const __bf16* __restrict__ qkv,
                                              const __bf16* __restrict__ vt,
                                              __bf16* __restrict__ ctx) {
    __shared__ __align__(16) unsigned char smem[18432];
    float* buf0 = (float*)smem;                    // [32][68] fp32, 8.7KB
    float* buf1 = (float*)(smem + 8704);           // 8.7KB
    float* Lsum = (float*)(smem + 17408);          // [4][32]
    float* Pmax = (float*)(smem + 17920);          // [4][32]

    int t = threadIdx.x, lane = t & 63, w = t >> 6;
    int quad = lane >> 4, n16 = lane & 15;
    // XCD-pinned swizzle: batch = id&7 pins each batch's K/V to one XCD's L2
    int id = blockIdx.x;
    int bB = id & 7;
    int seq = id >> 3;
    int h = seq % 12;
    int qt = seq / 12;
    int q0 = qt * 32;
    int bh = bB * NH + h;

    // Q fragments (B-operand of 16x16x32): qf[ng][kfi]; Q pre-scaled by CS in GEMM
    bf16x8 qf[2][2];
    {
        const __bf16* qbase = qkv + (size_t)(bB * NSEQ + q0 + n16) * NQKV + h * 64 + quad * 8;
#pragma unroll
        for (int ng = 0; ng < 2; ng++)
#pragma unroll
            for (int kfi = 0; kfi < 2; kfi++)
                qf[ng][kfi] = *(const bf16x8*)(qbase + (size_t)(ng * 16) * NQKV + kfi * 32);
    }

    // direct-load bases: K rows w*16+n16 (A-frag), V^T rows hd=n16 (A-frag of K=16)
    const __bf16* kb = qkv + (size_t)(bB * NSEQ + w * 16 + n16) * NQKV + 768 + h * 64 + quad * 8;
    const __bf16* vb = vt + (size_t)(bh * 64 + n16) * NSEQ + w * 16 + quad * 4;

    floatx4 acc[4][2] = {};               // O^T partial: [mg=hd group][ng=qrow group]
    float rs[2] = {0.f, 0.f};             // sum(p) per qrow ng*16+n16, wave's keys
    float pm[2] = {0.f, 0.f};             // max(p) likewise

    for (int kt = 0; kt < 16; kt++) {
        // K fragments: wave's 16 keys, 2x16B per lane (contiguous 64B/row segments)
        bf16x8 kf[2];
        kf[0] = *(const bf16x8*)kb;
        kf[1] = *(const bf16x8*)(kb + 32);
        // V^T fragments: hd = mg*16+n16, keys w*16+quad*4..+3, 8B per lane
        bf16x4 vf[4];
#pragma unroll
        for (int mg = 0; mg < 4; mg++)
            vf[mg] = *(const bf16x4*)(vb + (size_t)mg * 16 * NSEQ);
        kb += 64 * NQKV;
        vb += 64;

        // S^T: lane holds keys w*16+quad*4+r, qrows q0+ng*16+n16
        floatx4 s[2] = {};
#pragma unroll
        for (int ng = 0; ng < 2; ng++)
#pragma unroll
            for (int kfi = 0; kfi < 2; kfi++)
                s[ng] = mfma16x32(kf[kfi], qf[ng][kfi], s[ng]);

        // p = 2^s (Q pre-scaled); per-lane sum & max; bf16 for PV B-operand
        bf16x4 pb[2];
#pragma unroll
        for (int ng = 0; ng < 2; ng++) {
#pragma unroll
            for (int r = 0; r < 4; r++) {
                float p = __builtin_amdgcn_exp2f(s[ng][r]);
                rs[ng] += p;
                pm[ng] = fmaxf(pm[ng], p);
                pb[ng][r] = (__bf16)p;
            }
        }

        // O^T += V^T_sub · P^T_sub, K=16 register-direct
#pragma unroll
        for (int mg = 0; mg < 4; mg++)
#pragma unroll
            for (int ng = 0; ng < 2; ng++)
                acc[mg][ng] = mfma16x16(vf[mg], pb[ng], acc[mg][ng]);
    }

    // reduce sum/max across quads (quads held disjoint keys)
#pragma unroll
    for (int ng = 0; ng < 2; ng++) {
        rs[ng] += __shfl_xor(rs[ng], 16);
        rs[ng] += __shfl_xor(rs[ng], 32);
        pm[ng] = fmaxf(pm[ng], __shfl_xor(pm[ng], 16));
        pm[ng] = fmaxf(pm[ng], __shfl_xor(pm[ng], 32));
    }
    if (quad < 2) {
        Lsum[w * 32 + quad * 16 + n16] = quad ? rs[1] : rs[0];
        Pmax[w * 32 + quad * 16 + n16] = quad ? pm[1] : pm[0];
    }
    __syncthreads();

    // cross-wave O reduction: b128 stores, [qrow][hd] stride 68 (2-way = free)
    float* mybuf = (w & 1) ? buf1 : buf0;
    if (w < 2) {
#pragma unroll
        for (int mg = 0; mg < 4; mg++)
#pragma unroll
            for (int ng = 0; ng < 2; ng++)
                *(floatx4*)&mybuf[(ng * 16 + n16) * 68 + mg * 16 + quad * 4] = acc[mg][ng];
    }
    __syncthreads();
    if (w >= 2) {
#pragma unroll
        for (int mg = 0; mg < 4; mg++)
#pragma unroll
            for (int ng = 0; ng < 2; ng++) {
                float* p = &mybuf[(ng * 16 + n16) * 68 + mg * 16 + quad * 4];
                floatx4 cur = *(const floatx4*)p;
                *(floatx4*)p = cur + acc[mg][ng];
            }
    }
    __syncthreads();

    // final: out[qrow][hd] = (buf0+buf1) / (pmax + l); coalesced 16B stores
    int qrow = t >> 3;
    int hh = (t & 7) * 8;
    float l = Lsum[qrow] + Lsum[32 + qrow] + Lsum[64 + qrow] + Lsum[96 + qrow];
    float pmx = fmaxf(fmaxf(Pmax[qrow], Pmax[32 + qrow]),
                      fmaxf(Pmax[64 + qrow], Pmax[96 + qrow]));
    float invd = 1.f / (pmx + l);
    floatx4 v0 = *(const floatx4*)&buf0[qrow * 68 + hh];
    floatx4 v1 = *(const floatx4*)&buf0[qrow * 68 + hh + 4];
    floatx4 u0 = *(const floatx4*)&buf1[qrow * 68 + hh];
    floatx4 u1 = *(const floatx4*)&buf1[qrow * 68 + hh + 4];
    bf16x8 o;
#pragma unroll
    for (int j = 0; j < 4; j++) o[j] = (__bf16)((v0[j] + u0[j]) * invd);
#pragma unroll
    for (int j = 0; j < 4; j++) o[j + 4] = (__bf16)((v1[j] + u1[j]) * invd);
    __bf16* dst = ctx + (size_t)(bB * NSEQ + q0 + qrow) * DMODEL + h * 64 + hh;
    *(bf16x8*)dst = o;
}

extern "C" void kernel_launch(void* const* d_in, const int* in_sizes, int n_in,
                              void* d_out, int out_size, void* d_ws, size_t ws_size,
                              hipStream_t stream) {
    (void)in_sizes; (void)n_in; (void)out_size;
    const float* x  = (const float*)d_in[0];
    const float* Wq = (const float*)d_in[1];
    const float* bq = (const float*)d_in[2];
    const float* Wk = (const float*)d_in[3];
    const float* bk = (const float*)d_in[4];
    const float* Wv = (const float*)d_in[5];
    const float* bv = (const float*)d_in[6];
    const float* Wo = (const float*)d_in[7];
    const float* bo = (const float*)d_in[8];
    float* out = (float*)d_out;

    char* ws = (char*)d_ws;
    size_t off = 0;
    auto alloc = [&](size_t bytes) {
        void* p = ws + off;
        off += (bytes + 255) & ~(size_t)255;
        return p;
    };
    __bf16* xb    = (__bf16*)alloc((size_t)MTOK * DMODEL * 2);   // 12.6 MB (reused as ctx)
    __bf16* wtqkv = (__bf16*)alloc((size_t)NQKV * DMODEL * 2);   // 3.5 MB
    __bf16* wto   = (__bf16*)alloc((size_t)DMODEL * DMODEL * 2); // 1.2 MB
    float*  bqkv  = (float*)alloc((size_t)NQKV * 4);
    __bf16* qkvb  = (__bf16*)alloc((size_t)MTOK * NQKV * 2);     // 37.7 MB (V region unused)
    __bf16* vtb   = (__bf16*)alloc((size_t)BB * NH * HD * NSEQ * 2); // 12.6 MB
    if (off > ws_size) return;  // workspace too small -> visible failure
    __bf16* ctx = xb;  // xb dead after QKV GEMM

    k_convert_x<<<dim3(6144), dim3(256), 0, stream>>>(x, xb);
    k_bias<<<dim3(9), dim3(256), 0, stream>>>(bq, bk, bv, bqkv);
    k_transpose_w<<<dim3(24, 24, 4), dim3(256), 0, stream>>>(Wq, Wk, Wv, Wo, wtqkv, wto);
    k_gemm<__bf16, true><<<dim3(64, 18), dim3(256), 0, stream>>>(xb, wtqkv, bqkv, qkvb, NQKV, vtb);
    k_attn<<<dim3(3072), dim3(256), 0, stream>>>(qkvb, vtb, ctx);
    k_gemm<float, false><<<dim3(64, 6), dim3(256), 0, stream>>>(ctx, wto, bo, out, DMODEL, nullptr);
}

// Round 6
// 214.757 us; speedup vs baseline: 1.3996x; 1.3996x over previous
//
#include <hip/hip_runtime.h>
#include <cstdint>

#define DEV __device__ __forceinline__

typedef __bf16 bf16x4 __attribute__((ext_vector_type(4)));
typedef __bf16 bf16x8 __attribute__((ext_vector_type(8)));
typedef float  floatx4 __attribute__((ext_vector_type(4)));
typedef short  short4v __attribute__((ext_vector_type(4)));

constexpr int BB = 8, NSEQ = 1024, DMODEL = 768, NH = 12, HD = 64;
constexpr int MTOK = BB * NSEQ;   // 8192 tokens
constexpr int NQKV = 3 * DMODEL;  // 2304
constexpr float CS = 0.18033688011112042f;  // (1/sqrt(64)) * log2(e), folded into Q

DEV void async_copy16(void* lds, const void* g) {
    // global -> LDS direct copy, 16B/lane. LDS dest must be wave-base + lane*16.
    __builtin_amdgcn_global_load_lds(
        (__attribute__((address_space(1))) void*)(const_cast<void*>(g)),
        (__attribute__((address_space(3))) void*)lds,
        16, 0, 0);
}

DEV floatx4 mfma16x32(bf16x8 a, bf16x8 b, floatx4 c) {
    return __builtin_amdgcn_mfma_f32_16x16x32_bf16(a, b, c, 0, 0, 0);
}
DEV floatx4 mfma16x16(bf16x4 a, bf16x4 b, floatx4 c) {
    // K=16 bf16 MFMA: operand k = quad*4+j  == S^T C/D row layout (key=quad*4+r)
    return __builtin_amdgcn_mfma_f32_16x16x16bf16_1k(
        __builtin_bit_cast(short4v, a), __builtin_bit_cast(short4v, b), c, 0, 0, 0);
}

// Fragment-linear layouts (element indices), bh = b*12+h:
//  QF/KF: [bh][t16 = row>>4][kfi][lane = quad*16 + (row&15)][j=hd&7]
//         idx = ((bh*64 + t16)*2 + kfi)*512 + lane*8 + j  (kfi = hd>>5, quad=(hd>>3)&3)
//  VF:    [bh][kt64][w][mg][lane = ((key>>2)&3)*16 + (hd&15)][j=key&3]
//         idx = (((bh*16 + kt)*4 + w)*4 + mg)*256 + lane*4 + j  (w=(key>>4)&3, mg=hd>>4)
// Attention loads become base + lane*16B / lane*8B: perfectly coalesced.

// ---------------- x fp32 -> bf16 ----------------
__global__ __launch_bounds__(256) void k_convert_x(const float* __restrict__ x,
                                                   __bf16* __restrict__ xb) {
    int i = (blockIdx.x * 256 + threadIdx.x) * 4;  // grid sized exactly
    float4 v = *(const float4*)(x + i);
    bf16x4 o;
    o[0] = (__bf16)v.x; o[1] = (__bf16)v.y; o[2] = (__bf16)v.z; o[3] = (__bf16)v.w;
    *(bf16x4*)(xb + i) = o;
}

// ---------------- bias concat (q|k|v) fp32 ----------------
__global__ __launch_bounds__(256) void k_bias(const float* __restrict__ bq,
                                              const float* __restrict__ bk,
                                              const float* __restrict__ bv,
                                              float* __restrict__ out) {
    int i = blockIdx.x * 256 + threadIdx.x;  // grid = 9 -> 2304 exact
    if (i < 768) out[i] = bq[i];
    else if (i < 1536) out[i] = bk[i - 768];
    else if (i < 2304) out[i] = bv[i - 1536];
}

// ---------------- W [K,N] fp32 -> Wt [N,K] bf16 (z: 0=q 1=k 2=v 3=o) ----------------
__global__ __launch_bounds__(256) void k_transpose_w(const float* __restrict__ Wq,
                                                     const float* __restrict__ Wk,
                                                     const float* __restrict__ Wv,
                                                     const float* __restrict__ Wo,
                                                     __bf16* __restrict__ wtqkv,
                                                     __bf16* __restrict__ wto) {
    __shared__ float tile[32][33];
    int z = blockIdx.z;
    const float* W = (z == 0) ? Wq : (z == 1) ? Wk : (z == 2) ? Wv : Wo;
    int k0 = blockIdx.x * 32, n0 = blockIdx.y * 32;
    int tx = threadIdx.x & 31, ty = threadIdx.x >> 5;
#pragma unroll
    for (int p = 0; p < 4; p++)
        tile[ty + 8 * p][tx] = W[(size_t)(k0 + ty + 8 * p) * 768 + n0 + tx];
    __syncthreads();
    __bf16* out = (z < 3) ? (wtqkv + (size_t)z * 768 * 768) : wto;
#pragma unroll
    for (int p = 0; p < 4; p++)
        out[(size_t)(n0 + ty + 8 * p) * 768 + k0 + tx] = (__bf16)tile[tx][ty + 8 * p];
}

// ---------------- GEMM: C[M,Nn] = A[M,768] @ Bt[Nn,768]^T + bias ----------------
// BM=BN=128, BK=64, 4 waves each 64x64 (4x4 acc of 16x16x32 MFMA).
// QKV=true: write Q (scaled by CS), K, V directly in fragment-linear layout.
template <typename OutT, bool QKV>
__global__ __launch_bounds__(256) void k_gemm(const __bf16* __restrict__ A,
                                              const __bf16* __restrict__ Bt,
                                              const float* __restrict__ bias,
                                              OutT* __restrict__ C, int Nn,
                                              __bf16* __restrict__ qfb,
                                              __bf16* __restrict__ kfb,
                                              __bf16* __restrict__ vfb) {
    __shared__ __align__(16) __bf16 As[128 * 64];
    __shared__ __align__(16) __bf16 Bs[128 * 64];
    int t = threadIdx.x, lane = t & 63, w = t >> 6;
    int quad = lane >> 4, n16 = lane & 15;
    int wm = w & 1, wn = w >> 1;
    int m0 = blockIdx.x * 128, n0 = blockIdx.y * 128;
    floatx4 acc[4][4] = {};

    for (int k0 = 0; k0 < 768; k0 += 64) {
        __syncthreads();
#pragma unroll
        for (int i = 0; i < 4; i++) {  // stage A tile 128x64 (16KB)
            int off = t + i * 256;
            int row = off >> 3, pc = off & 7;
            int c = pc ^ (row & 7);
            async_copy16(&As[row * 64 + pc * 8],
                         &A[(size_t)(m0 + row) * 768 + k0 + c * 8]);
        }
#pragma unroll
        for (int i = 0; i < 4; i++) {  // stage B tile 128x64
            int off = t + i * 256;
            int row = off >> 3, pc = off & 7;
            int c = pc ^ (row & 7);
            async_copy16(&Bs[row * 64 + pc * 8],
                         &Bt[(size_t)(n0 + row) * 768 + k0 + c * 8]);
        }
        __builtin_amdgcn_s_waitcnt(0);  // drain global_load_lds before barrier
        __syncthreads();
#pragma unroll
        for (int kfi = 0; kfi < 2; kfi++) {
            bf16x8 a[4], bfr[4];
#pragma unroll
            for (int rt = 0; rt < 4; rt++) {
                int row = wm * 64 + rt * 16 + n16;
                a[rt] = *(const bf16x8*)&As[row * 64 + ((quad + 4 * kfi) ^ (row & 7)) * 8];
            }
#pragma unroll
            for (int ct = 0; ct < 4; ct++) {
                int row = wn * 64 + ct * 16 + n16;
                bfr[ct] = *(const bf16x8*)&Bs[row * 64 + ((quad + 4 * kfi) ^ (row & 7)) * 8];
            }
#pragma unroll
            for (int rt = 0; rt < 4; rt++)
#pragma unroll
                for (int ct = 0; ct < 4; ct++)
                    acc[rt][ct] = mfma16x32(a[rt], bfr[ct], acc[rt][ct]);
        }
    }
    // epilogue: C/D layout col=lane&15, row=quad*4+reg. Zone is block-uniform
    // (n0 multiples of 128; boundaries 768/1536 are too).
    if (QKV) {
        if (n0 >= 1536) {
            // V -> VF fragment-linear
#pragma unroll
            for (int ct = 0; ct < 4; ct++) {
                int col = n0 + wn * 64 + ct * 16 + n16;
                float bs = bias[col];
                int cz = col - 1536;
                int hh = cz >> 6, hd = cz & 63;
                int mg = hd >> 4, l16 = hd & 15;
#pragma unroll
                for (int rt = 0; rt < 4; rt++) {
                    int row0 = m0 + wm * 64 + rt * 16 + quad * 4;
                    int bb = row0 >> 10, key = row0 & 1023;
                    int kt = key >> 6, wv = (key >> 4) & 3, qd = (key >> 2) & 3;
                    bf16x4 pk;
#pragma unroll
                    for (int r = 0; r < 4; r++) pk[r] = (__bf16)(acc[rt][ct][r] + bs);
                    size_t idx = ((((size_t)(bb * 12 + hh) * 16 + kt) * 4 + wv) * 4 + mg) * 256
                                 + (size_t)(qd * 16 + l16) * 4;
                    *(bf16x4*)&vfb[idx] = pk;
                }
            }
        } else {
            __bf16* dst = (n0 < 768) ? qfb : kfb;
            float mult = (n0 < 768) ? CS : 1.0f;
            int cofs = (n0 < 768) ? 0 : 768;
#pragma unroll
            for (int ct = 0; ct < 4; ct++) {
                int col = n0 + wn * 64 + ct * 16 + n16;
                float bs = bias[col];
                int cz = col - cofs;
                int hh = cz >> 6, hd = cz & 63;
                int kfi = hd >> 5, qd2 = (hd >> 3) & 3, j = hd & 7;
#pragma unroll
                for (int rt = 0; rt < 4; rt++) {
                    int row0 = m0 + wm * 64 + rt * 16 + quad * 4;
                    int bb = row0 >> 10, q = row0 & 1023;
                    int t16 = q >> 4, nn = q & 15;  // q%4==0 -> nn+r stays <16
                    size_t idx = (((size_t)(bb * 12 + hh) * 64 + t16) * 2 + kfi) * 512
                                 + (size_t)(qd2 * 16 + nn) * 8 + j;
#pragma unroll
                    for (int r = 0; r < 4; r++)
                        dst[idx + (size_t)r * 8] = (__bf16)((acc[rt][ct][r] + bs) * mult);
                }
            }
        }
    } else {
#pragma unroll
        for (int ct = 0; ct < 4; ct++) {
            int col = n0 + wn * 64 + ct * 16 + n16;
            float bs = bias[col];
#pragma unroll
            for (int rt = 0; rt < 4; rt++) {
#pragma unroll
                for (int r = 0; r < 4; r++) {
                    int row = m0 + wm * 64 + rt * 16 + quad * 4 + r;
                    C[(size_t)row * Nn + col] = (OutT)(acc[rt][ct][r] + bs);
                }
            }
        }
    }
}

// ---------------- flash attention: barrier-free loop, fragment-linear loads ----------------
// Block = 32 qrows of one (b,h); wave w owns keys [kt*64+w*16, +16) each iter.
// Q/K/V pre-stored in MFMA-fragment order -> every load is base + lane*(16|8)B,
// perfectly coalesced, L2-resident (XCD-pinned). Explicit depth-1 register
// double-buffer keeps next iter's loads in flight during compute.
// S^T = K_sub·Q^T (16x16x32); P feeds PV register-direct via K=16 MFMA.
// Quiet softmax exact identity: out = p / (max(p) + sum(p)), p = 2^(s_scaled).
__global__ __launch_bounds__(256) void k_attn(const __bf16* __restrict__ QF,
                                              const __bf16* __restrict__ KF,
                                              const __bf16* __restrict__ VF,
                                              __bf16* __restrict__ ctx) {
    __shared__ __align__(16) unsigned char smem[18432];
    float* buf0 = (float*)smem;                    // [32][68] fp32, 8.7KB
    float* buf1 = (float*)(smem + 8704);           // 8.7KB
    float* Lsum = (float*)(smem + 17408);          // [4][32]
    float* Pmax = (float*)(smem + 17920);          // [4][32]

    int t = threadIdx.x, lane = t & 63, w = t >> 6;
    int quad = lane >> 4, n16 = lane & 15;
    // XCD-pinned swizzle: batch = id&7 pins each batch's K/V to one XCD's L2
    int id = blockIdx.x;
    int bB = id & 7;
    int seq = id >> 3;
    int h = seq % 12;
    int qt = seq / 12;
    int q0 = qt * 32;
    int bh = bB * NH + h;

    // Q fragments: coalesced frag-linear loads
    bf16x8 qf[2][2];
    {
        const __bf16* qp = QF + (size_t)(bh * 64 + qt * 2) * 1024 + lane * 8;
#pragma unroll
        for (int ng = 0; ng < 2; ng++)
#pragma unroll
            for (int kfi = 0; kfi < 2; kfi++)
                qf[ng][kfi] = *(const bf16x8*)(qp + (ng * 2 + kfi) * 512);
    }
    const __bf16* kp = KF + (size_t)(bh * 64 + w) * 1024 + lane * 8;
    const __bf16* vp = VF + ((size_t)bh * 16 * 4 + w) * 1024 + lane * 4;

    floatx4 acc[4][2] = {};               // O^T partial: [mg=hd group][ng=qrow group]
    float rs[2] = {0.f, 0.f};             // sum(p) per qrow ng*16+n16, wave's keys
    float pm[2] = {0.f, 0.f};             // max(p) likewise

    auto compute = [&](bf16x8 (&kf)[2], bf16x4 (&vf)[4]) {
        floatx4 s[2] = {};
#pragma unroll
        for (int ng = 0; ng < 2; ng++)
#pragma unroll
            for (int kfi = 0; kfi < 2; kfi++)
                s[ng] = mfma16x32(kf[kfi], qf[ng][kfi], s[ng]);
        bf16x4 pb[2];
#pragma unroll
        for (int ng = 0; ng < 2; ng++) {
#pragma unroll
            for (int r = 0; r < 4; r++) {
                float p = __builtin_amdgcn_exp2f(s[ng][r]);
                rs[ng] += p;
                pm[ng] = fmaxf(pm[ng], p);
                pb[ng][r] = (__bf16)p;
            }
        }
#pragma unroll
        for (int mg = 0; mg < 4; mg++)
#pragma unroll
            for (int ng = 0; ng < 2; ng++)
                acc[mg][ng] = mfma16x16(vf[mg], pb[ng], acc[mg][ng]);
    };

    // software pipeline, depth 1, two named register sets
    bf16x8 kf0[2], kf1[2];
    bf16x4 vf0[4], vf1[4];
    kf0[0] = *(const bf16x8*)kp;
    kf0[1] = *(const bf16x8*)(kp + 512);
#pragma unroll
    for (int mg = 0; mg < 4; mg++) vf0[mg] = *(const bf16x4*)(vp + mg * 256);
    kp += 4096; vp += 4096;

    for (int kt = 0; kt < 16; kt += 2) {
        kf1[0] = *(const bf16x8*)kp;
        kf1[1] = *(const bf16x8*)(kp + 512);
#pragma unroll
        for (int mg = 0; mg < 4; mg++) vf1[mg] = *(const bf16x4*)(vp + mg * 256);
        kp += 4096; vp += 4096;
        compute(kf0, vf0);
        if (kt < 14) {
            kf0[0] = *(const bf16x8*)kp;
            kf0[1] = *(const bf16x8*)(kp + 512);
#pragma unroll
            for (int mg = 0; mg < 4; mg++) vf0[mg] = *(const bf16x4*)(vp + mg * 256);
            kp += 4096; vp += 4096;
        }
        compute(kf1, vf1);
    }

    // reduce sum/max across quads (quads held disjoint keys)
#pragma unroll
    for (int ng = 0; ng < 2; ng++) {
        rs[ng] += __shfl_xor(rs[ng], 16);
        rs[ng] += __shfl_xor(rs[ng], 32);
        pm[ng] = fmaxf(pm[ng], __shfl_xor(pm[ng], 16));
        pm[ng] = fmaxf(pm[ng], __shfl_xor(pm[ng], 32));
    }
    if (quad < 2) {
        Lsum[w * 32 + quad * 16 + n16] = quad ? rs[1] : rs[0];
        Pmax[w * 32 + quad * 16 + n16] = quad ? pm[1] : pm[0];
    }
    __syncthreads();

    // cross-wave O reduction: b128 stores, [qrow][hd] stride 68 (2-way = free)
    float* mybuf = (w & 1) ? buf1 : buf0;
    if (w < 2) {
#pragma unroll
        for (int mg = 0; mg < 4; mg++)
#pragma unroll
            for (int ng = 0; ng < 2; ng++)
                *(floatx4*)&mybuf[(ng * 16 + n16) * 68 + mg * 16 + quad * 4] = acc[mg][ng];
    }
    __syncthreads();
    if (w >= 2) {
#pragma unroll
        for (int mg = 0; mg < 4; mg++)
#pragma unroll
            for (int ng = 0; ng < 2; ng++) {
                float* p = &mybuf[(ng * 16 + n16) * 68 + mg * 16 + quad * 4];
                floatx4 cur = *(const floatx4*)p;
                *(floatx4*)p = cur + acc[mg][ng];
            }
    }
    __syncthreads();

    // final: out[qrow][hd] = (buf0+buf1) / (pmax + l); coalesced 16B stores
    int qrow = t >> 3;
    int hh = (t & 7) * 8;
    float l = Lsum[qrow] + Lsum[32 + qrow] + Lsum[64 + qrow] + Lsum[96 + qrow];
    float pmx = fmaxf(fmaxf(Pmax[qrow], Pmax[32 + qrow]),
                      fmaxf(Pmax[64 + qrow], Pmax[96 + qrow]));
    float invd = 1.f / (pmx + l);
    floatx4 v0 = *(const floatx4*)&buf0[qrow * 68 + hh];
    floatx4 v1 = *(const floatx4*)&buf0[qrow * 68 + hh + 4];
    floatx4 u0 = *(const floatx4*)&buf1[qrow * 68 + hh];
    floatx4 u1 = *(const floatx4*)&buf1[qrow * 68 + hh + 4];
    bf16x8 o;
#pragma unroll
    for (int j = 0; j < 4; j++) o[j] = (__bf16)((v0[j] + u0[j]) * invd);
#pragma unroll
    for (int j = 0; j < 4; j++) o[j + 4] = (__bf16)((v1[j] + u1[j]) * invd);
    __bf16* dst = ctx + (size_t)(bB * NSEQ + q0 + qrow) * DMODEL + h * 64 + hh;
    *(bf16x8*)dst = o;
}

extern "C" void kernel_launch(void* const* d_in, const int* in_sizes, int n_in,
                              void* d_out, int out_size, void* d_ws, size_t ws_size,
                              hipStream_t stream) {
    (void)in_sizes; (void)n_in; (void)out_size;
    const float* x  = (const float*)d_in[0];
    const float* Wq = (const float*)d_in[1];
    const float* bq = (const float*)d_in[2];
    const float* Wk = (const float*)d_in[3];
    const float* bk = (const float*)d_in[4];
    const float* Wv = (const float*)d_in[5];
    const float* bv = (const float*)d_in[6];
    const float* Wo = (const float*)d_in[7];
    const float* bo = (const float*)d_in[8];
    float* out = (float*)d_out;

    char* ws = (char*)d_ws;
    size_t off = 0;
    auto alloc = [&](size_t bytes) {
        void* p = ws + off;
        off += (bytes + 255) & ~(size_t)255;
        return p;
    };
    __bf16* xb    = (__bf16*)alloc((size_t)MTOK * DMODEL * 2);   // 12.6 MB (reused as ctx)
    __bf16* wtqkv = (__bf16*)alloc((size_t)NQKV * DMODEL * 2);   // 3.5 MB
    __bf16* wto   = (__bf16*)alloc((size_t)DMODEL * DMODEL * 2); // 1.2 MB
    float*  bqkv  = (float*)alloc((size_t)NQKV * 4);
    __bf16* qfb   = (__bf16*)alloc((size_t)MTOK * DMODEL * 2);   // 12.6 MB frag-linear Q
    __bf16* kfb   = (__bf16*)alloc((size_t)MTOK * DMODEL * 2);   // 12.6 MB frag-linear K
    __bf16* vfb   = (__bf16*)alloc((size_t)MTOK * DMODEL * 2);   // 12.6 MB frag-linear V
    if (off > ws_size) return;  // workspace too small -> visible failure
    __bf16* ctx = xb;  // xb dead after QKV GEMM

    k_convert_x<<<dim3(6144), dim3(256), 0, stream>>>(x, xb);
    k_bias<<<dim3(9), dim3(256), 0, stream>>>(bq, bk, bv, bqkv);
    k_transpose_w<<<dim3(24, 24, 4), dim3(256), 0, stream>>>(Wq, Wk, Wv, Wo, wtqkv, wto);
    k_gemm<__bf16, true><<<dim3(64, 18), dim3(256), 0, stream>>>(
        xb, wtqkv, bqkv, (__bf16*)nullptr, NQKV, qfb, kfb, vfb);
    k_attn<<<dim3(3072), dim3(256), 0, stream>>>(qfb, kfb, vfb, ctx);
    k_gemm<float, false><<<dim3(64, 6), dim3(256), 0, stream>>>(
        ctx, wto, bo, out, DMODEL, nullptr, nullptr, nullptr);
}

// Round 9
// 205.253 us; speedup vs baseline: 1.4644x; 1.0463x over previous
//
#include <hip/hip_runtime.h>
#include <cstdint>

#define DEV __device__ __forceinline__

typedef __bf16 bf16x4 __attribute__((ext_vector_type(4)));
typedef __bf16 bf16x8 __attribute__((ext_vector_type(8)));
typedef float  floatx4 __attribute__((ext_vector_type(4)));
typedef short  short4v __attribute__((ext_vector_type(4)));

constexpr int BB = 8, NSEQ = 1024, DMODEL = 768, NH = 12, HD = 64;
constexpr int MTOK = BB * NSEQ;   // 8192 tokens
constexpr int NQKV = 3 * DMODEL;  // 2304
constexpr float CS = 0.18033688011112042f;  // (1/sqrt(64)) * log2(e), folded into Q

DEV void async_copy16(void* lds, const void* g) {
    // global -> LDS direct copy, 16B/lane. LDS dest must be wave-base + lane*16.
    __builtin_amdgcn_global_load_lds(
        (__attribute__((address_space(1))) void*)(const_cast<void*>(g)),
        (__attribute__((address_space(3))) void*)lds,
        16, 0, 0);
}

DEV floatx4 mfma16x32(bf16x8 a, bf16x8 b, floatx4 c) {
    return __builtin_amdgcn_mfma_f32_16x16x32_bf16(a, b, c, 0, 0, 0);
}
DEV floatx4 mfma16x16(bf16x4 a, bf16x4 b, floatx4 c) {
    // K=16 bf16 MFMA: operand k = quad*4+j  == S^T C/D row layout (key=quad*4+r)
    return __builtin_amdgcn_mfma_f32_16x16x16bf16_1k(
        __builtin_bit_cast(short4v, a), __builtin_bit_cast(short4v, b), c, 0, 0, 0);
}

// Fragment-linear layouts (element indices), bh = b*12+h:
//  QF/KF: idx = ((bh*64 + t16)*2 + kfi)*512 + (quad*16 + (row&15))*8 + (hd&7)
//  VF:    idx = (((bh*16 + kt)*4 + w)*4 + mg)*256 + (((key>>2)&3)*16 + (hd&15))*4 + (key&3)
// Attention loads become base + lane*16B / lane*8B: perfectly coalesced.

// ---------------- fused prep: x->bf16 | W transpose->bf16 | bias concat ----------------
__global__ __launch_bounds__(256) void k_prep(const float* __restrict__ x,
                                              __bf16* __restrict__ xb,
                                              const float* __restrict__ Wq,
                                              const float* __restrict__ Wk,
                                              const float* __restrict__ Wv,
                                              const float* __restrict__ Wo,
                                              __bf16* __restrict__ wtqkv,
                                              __bf16* __restrict__ wto,
                                              const float* __restrict__ bq,
                                              const float* __restrict__ bk,
                                              const float* __restrict__ bv,
                                              float* __restrict__ bqkv) {
    __shared__ float tile[32][33];
    int bid = blockIdx.x, t = threadIdx.x;
    if (bid < 6144) {                       // x fp32 -> bf16, 4 elem/thread
        int i = (bid * 256 + t) * 4;
        float4 v = *(const float4*)(x + i);
        bf16x4 o;
        o[0] = (__bf16)v.x; o[1] = (__bf16)v.y; o[2] = (__bf16)v.z; o[3] = (__bf16)v.w;
        *(bf16x4*)(xb + i) = o;
    } else if (bid < 8448) {                // W [K,N] -> Wt [N,K] bf16
        int idx = bid - 6144;
        int z = idx / 576, rem = idx % 576;
        int k0 = (rem % 24) * 32, n0 = (rem / 24) * 32;
        const float* W = (z == 0) ? Wq : (z == 1) ? Wk : (z == 2) ? Wv : Wo;
        int tx = t & 31, ty = t >> 5;
#pragma unroll
        for (int p = 0; p < 4; p++)
            tile[ty + 8 * p][tx] = W[(size_t)(k0 + ty + 8 * p) * 768 + n0 + tx];
        __syncthreads();
        __bf16* out = (z < 3) ? (wtqkv + (size_t)z * 768 * 768) : wto;
#pragma unroll
        for (int p = 0; p < 4; p++)
            out[(size_t)(n0 + ty + 8 * p) * 768 + k0 + tx] = (__bf16)tile[tx][ty + 8 * p];
    } else {                                // bias concat
        int i = (bid - 8448) * 256 + t;
        if (i < 768) bqkv[i] = bq[i];
        else if (i < 1536) bqkv[i] = bk[i - 768];
        else bqkv[i] = bv[i - 1536];
    }
}

// ---------------- GEMM: C[M,Nn] = A[M,768] @ Bt[Nn,768]^T + bias ----------------
// R6-proven 2-barrier structure: BK=64, full s_waitcnt(0)+__syncthreads per iter
// (manual partial-vmcnt pipelining is NOT reliably expressible from HIP source:
// compiler scratch/spill vmem ops silently corrupt the count -> R7/R8 races).
// BM=128, BN templated (128 for QKV fused epilogue, 64 for O-proj grid shape).
// 4 waves each cover (wm*64 rows) x (wn*(BN/2) cols), 4xCT acc of 16x16x32 MFMA.
// LDS rows are 8 chunks of 16B; chunk XOR-swizzled with (row&7).
template <typename OutT, bool QKV, int BN>
__global__ __launch_bounds__(256) void k_gemm(const __bf16* __restrict__ A,
                                              const __bf16* __restrict__ Bt,
                                              const float* __restrict__ bias,
                                              OutT* __restrict__ C, int Nn,
                                              __bf16* __restrict__ qfb,
                                              __bf16* __restrict__ kfb,
                                              __bf16* __restrict__ vfb) {
    constexpr int CT = BN / 32;        // col-tiles per wave (128->4, 64->2)
    constexpr int NBI = BN / 32;       // B staging insts/thread
    __shared__ __align__(16) __bf16 As[128 * 64];
    __shared__ __align__(16) __bf16 Bs[BN * 64];
    int t = threadIdx.x, lane = t & 63, w = t >> 6;
    int quad = lane >> 4, n16 = lane & 15;
    int wm = w & 1, wn = w >> 1;
    int m0 = blockIdx.x * 128, n0 = blockIdx.y * BN;
    floatx4 acc[4][CT] = {};

    for (int k0 = 0; k0 < 768; k0 += 64) {
        __syncthreads();
#pragma unroll
        for (int i = 0; i < 4; i++) {  // stage A tile 128x64 (16KB)
            int off = t + i * 256;
            int row = off >> 3, pc = off & 7;
            int c = pc ^ (row & 7);
            async_copy16(&As[row * 64 + pc * 8],
                         &A[(size_t)(m0 + row) * 768 + k0 + c * 8]);
        }
#pragma unroll
        for (int i = 0; i < NBI; i++) {  // stage B tile BNx64
            int off = t + i * 256;
            int row = off >> 3, pc = off & 7;
            int c = pc ^ (row & 7);
            async_copy16(&Bs[row * 64 + pc * 8],
                         &Bt[(size_t)(n0 + row) * 768 + k0 + c * 8]);
        }
        __builtin_amdgcn_s_waitcnt(0);  // drain global_load_lds before barrier
        __syncthreads();
#pragma unroll
        for (int kfi = 0; kfi < 2; kfi++) {
            bf16x8 a[4], bfr[CT];
#pragma unroll
            for (int rt = 0; rt < 4; rt++) {
                int row = wm * 64 + rt * 16 + n16;
                a[rt] = *(const bf16x8*)&As[row * 64 + ((quad + 4 * kfi) ^ (row & 7)) * 8];
            }
#pragma unroll
            for (int ct = 0; ct < CT; ct++) {
                int row = wn * (BN / 2) + ct * 16 + n16;
                bfr[ct] = *(const bf16x8*)&Bs[row * 64 + ((quad + 4 * kfi) ^ (row & 7)) * 8];
            }
#pragma unroll
            for (int rt = 0; rt < 4; rt++)
#pragma unroll
                for (int ct = 0; ct < CT; ct++)
                    acc[rt][ct] = mfma16x32(a[rt], bfr[ct], acc[rt][ct]);
        }
    }

    // epilogue: C/D layout col=lane&15, row=quad*4+reg. Zone is block-uniform.
    if (QKV) {
        if (n0 >= 1536) {
            // V -> VF fragment-linear, b64 stores
#pragma unroll
            for (int ct = 0; ct < CT; ct++) {
                int col = n0 + wn * (BN / 2) + ct * 16 + n16;
                float bs = bias[col];
                int cz = col - 1536;
                int hh = cz >> 6, hd = cz & 63;
                int mg = hd >> 4, l16 = hd & 15;
#pragma unroll
                for (int rt = 0; rt < 4; rt++) {
                    int row0 = m0 + wm * 64 + rt * 16 + quad * 4;
                    int bb = row0 >> 10, key = row0 & 1023;
                    int kt = key >> 6, wv = (key >> 4) & 3, qd = (key >> 2) & 3;
                    bf16x4 pk;
#pragma unroll
                    for (int r = 0; r < 4; r++) pk[r] = (__bf16)(acc[rt][ct][r] + bs);
                    size_t idx = ((((size_t)(bb * 12 + hh) * 16 + kt) * 4 + wv) * 4 + mg) * 256
                                 + (size_t)(qd * 16 + l16) * 4;
                    *(bf16x4*)&vfb[idx] = pk;
                }
            }
        } else {
            __bf16* dst = (n0 < 768) ? qfb : kfb;
            float mult = (n0 < 768) ? CS : 1.0f;
            int cofs = (n0 < 768) ? 0 : 768;
#pragma unroll
            for (int ct = 0; ct < CT; ct++) {
                int col = n0 + wn * (BN / 2) + ct * 16 + n16;
                float bs = bias[col];
                int cz = col - cofs;
                int hh = cz >> 6, hd = cz & 63;
                int kfi = hd >> 5, qd2 = (hd >> 3) & 3, j = hd & 7;
#pragma unroll
                for (int rt = 0; rt < 4; rt++) {
                    int row0 = m0 + wm * 64 + rt * 16 + quad * 4;
                    int bb = row0 >> 10, q = row0 & 1023;
                    int t16 = q >> 4, nn = q & 15;  // q%4==0 -> nn+r stays <16
                    size_t idx = (((size_t)(bb * 12 + hh) * 64 + t16) * 2 + kfi) * 512
                                 + (size_t)(qd2 * 16 + nn) * 8 + j;
#pragma unroll
                    for (int r = 0; r < 4; r++)
                        dst[idx + (size_t)r * 8] = (__bf16)((acc[rt][ct][r] + bs) * mult);
                }
            }
        }
    } else {
#pragma unroll
        for (int ct = 0; ct < CT; ct++) {
            int col = n0 + wn * (BN / 2) + ct * 16 + n16;
            float bs = bias[col];
#pragma unroll
            for (int rt = 0; rt < 4; rt++) {
#pragma unroll
                for (int r = 0; r < 4; r++) {
                    int row = m0 + wm * 64 + rt * 16 + quad * 4 + r;
                    C[(size_t)row * Nn + col] = (OutT)(acc[rt][ct][r] + bs);
                }
            }
        }
    }
}

// ---------------- flash attention: barrier-free loop, fragment-linear loads ----------------
// Block = 32 qrows of one (b,h); wave w owns keys [kt*64+w*16, +16) each iter.
// Q/K/V pre-stored in MFMA-fragment order -> every load is base + lane*(16|8)B,
// perfectly coalesced, L2-resident (XCD-pinned). Explicit depth-1 register
// double-buffer keeps next iter's loads in flight during compute.
// S^T = K_sub·Q^T (16x16x32); P feeds PV register-direct via K=16 MFMA.
// Quiet softmax exact identity: out = p / (max(p) + sum(p)), p = 2^(s_scaled).
__global__ __launch_bounds__(256) void k_attn(const __bf16* __restrict__ QF,
                                              const __bf16* __restrict__ KF,
                                              const __bf16* __restrict__ VF,
                                              __bf16* __restrict__ ctx) {
    __shared__ __align__(16) unsigned char smem[18432];
    float* buf0 = (float*)smem;                    // [32][68] fp32, 8.7KB
    float* buf1 = (float*)(smem + 8704);           // 8.7KB
    float* Lsum = (float*)(smem + 17408);          // [4][32]
    float* Pmax = (float*)(smem + 17920);          // [4][32]

    int t = threadIdx.x, lane = t & 63, w = t >> 6;
    int quad = lane >> 4, n16 = lane & 15;
    // XCD-pinned swizzle: batch = id&7 pins each batch's K/V to one XCD's L2
    int id = blockIdx.x;
    int bB = id & 7;
    int seq = id >> 3;
    int h = seq % 12;
    int qt = seq / 12;
    int q0 = qt * 32;
    int bh = bB * NH + h;

    // Q fragments: coalesced frag-linear loads
    bf16x8 qf[2][2];
    {
        const __bf16* qp = QF + (size_t)(bh * 64 + qt * 2) * 1024 + lane * 8;
#pragma unroll
        for (int ng = 0; ng < 2; ng++)
#pragma unroll
            for (int kfi = 0; kfi < 2; kfi++)
                qf[ng][kfi] = *(const bf16x8*)(qp + (ng * 2 + kfi) * 512);
    }
    const __bf16* kp = KF + (size_t)(bh * 64 + w) * 1024 + lane * 8;
    const __bf16* vp = VF + ((size_t)bh * 16 * 4 + w) * 1024 + lane * 4;

    floatx4 acc[4][2] = {};               // O^T partial: [mg=hd group][ng=qrow group]
    float rs[2] = {0.f, 0.f};             // sum(p) per qrow ng*16+n16, wave's keys
    float pm[2] = {0.f, 0.f};             // max(p) likewise

    auto compute = [&](bf16x8 (&kf)[2], bf16x4 (&vf)[4]) {
        floatx4 s[2] = {};
#pragma unroll
        for (int ng = 0; ng < 2; ng++)
#pragma unroll
            for (int kfi = 0; kfi < 2; kfi++)
                s[ng] = mfma16x32(kf[kfi], qf[ng][kfi], s[ng]);
        bf16x4 pb[2];
#pragma unroll
        for (int ng = 0; ng < 2; ng++) {
#pragma unroll
            for (int r = 0; r < 4; r++) {
                float p = __builtin_amdgcn_exp2f(s[ng][r]);
                rs[ng] += p;
                pm[ng] = fmaxf(pm[ng], p);
                pb[ng][r] = (__bf16)p;
            }
        }
#pragma unroll
        for (int mg = 0; mg < 4; mg++)
#pragma unroll
            for (int ng = 0; ng < 2; ng++)
                acc[mg][ng] = mfma16x16(vf[mg], pb[ng], acc[mg][ng]);
    };

    // software pipeline, depth 1, two named register sets
    bf16x8 kf0[2], kf1[2];
    bf16x4 vf0[4], vf1[4];
    kf0[0] = *(const bf16x8*)kp;
    kf0[1] = *(const bf16x8*)(kp + 512);
#pragma unroll
    for (int mg = 0; mg < 4; mg++) vf0[mg] = *(const bf16x4*)(vp + mg * 256);
    kp += 4096; vp += 4096;

    for (int kt = 0; kt < 16; kt += 2) {
        kf1[0] = *(const bf16x8*)kp;
        kf1[1] = *(const bf16x8*)(kp + 512);
#pragma unroll
        for (int mg = 0; mg < 4; mg++) vf1[mg] = *(const bf16x4*)(vp + mg * 256);
        kp += 4096; vp += 4096;
        compute(kf0, vf0);
        if (kt < 14) {
            kf0[0] = *(const bf16x8*)kp;
            kf0[1] = *(const bf16x8*)(kp + 512);
#pragma unroll
            for (int mg = 0; mg < 4; mg++) vf0[mg] = *(const bf16x4*)(vp + mg * 256);
            kp += 4096; vp += 4096;
        }
        compute(kf1, vf1);
    }

    // reduce sum/max across quads (quads held disjoint keys)
#pragma unroll
    for (int ng = 0; ng < 2; ng++) {
        rs[ng] += __shfl_xor(rs[ng], 16);
        rs[ng] += __shfl_xor(rs[ng], 32);
        pm[ng] = fmaxf(pm[ng], __shfl_xor(pm[ng], 16));
        pm[ng] = fmaxf(pm[ng], __shfl_xor(pm[ng], 32));
    }
    if (quad < 2) {
        Lsum[w * 32 + quad * 16 + n16] = quad ? rs[1] : rs[0];
        Pmax[w * 32 + quad * 16 + n16] = quad ? pm[1] : pm[0];
    }
    __syncthreads();

    // cross-wave O reduction: b128 stores, [qrow][hd] stride 68 (2-way = free)
    float* mybuf = (w & 1) ? buf1 : buf0;
    if (w < 2) {
#pragma unroll
        for (int mg = 0; mg < 4; mg++)
#pragma unroll
            for (int ng = 0; ng < 2; ng++)
                *(floatx4*)&mybuf[(ng * 16 + n16) * 68 + mg * 16 + quad * 4] = acc[mg][ng];
    }
    __syncthreads();
    if (w >= 2) {
#pragma unroll
        for (int mg = 0; mg < 4; mg++)
#pragma unroll
            for (int ng = 0; ng < 2; ng++) {
                float* p = &mybuf[(ng * 16 + n16) * 68 + mg * 16 + quad * 4];
                floatx4 cur = *(const floatx4*)p;
                *(floatx4*)p = cur + acc[mg][ng];
            }
    }
    __syncthreads();

    // final: out[qrow][hd] = (buf0+buf1) / (pmax + l); coalesced 16B stores
    int qrow = t >> 3;
    int hh = (t & 7) * 8;
    float l = Lsum[qrow] + Lsum[32 + qrow] + Lsum[64 + qrow] + Lsum[96 + qrow];
    float pmx = fmaxf(fmaxf(Pmax[qrow], Pmax[32 + qrow]),
                      fmaxf(Pmax[64 + qrow], Pmax[96 + qrow]));
    float invd = 1.f / (pmx + l);
    floatx4 v0 = *(const floatx4*)&buf0[qrow * 68 + hh];
    floatx4 v1 = *(const floatx4*)&buf0[qrow * 68 + hh + 4];
    floatx4 u0 = *(const floatx4*)&buf1[qrow * 68 + hh];
    floatx4 u1 = *(const floatx4*)&buf1[qrow * 68 + hh + 4];
    bf16x8 o;
#pragma unroll
    for (int j = 0; j < 4; j++) o[j] = (__bf16)((v0[j] + u0[j]) * invd);
#pragma unroll
    for (int j = 0; j < 4; j++) o[j + 4] = (__bf16)((v1[j] + u1[j]) * invd);
    __bf16* dst = ctx + (size_t)(bB * NSEQ + q0 + qrow) * DMODEL + h * 64 + hh;
    *(bf16x8*)dst = o;
}

extern "C" void kernel_launch(void* const* d_in, const int* in_sizes, int n_in,
                              void* d_out, int out_size, void* d_ws, size_t ws_size,
                              hipStream_t stream) {
    (void)in_sizes; (void)n_in; (void)out_size;
    const float* x  = (const float*)d_in[0];
    const float* Wq = (const float*)d_in[1];
    const float* bq = (const float*)d_in[2];
    const float* Wk = (const float*)d_in[3];
    const float* bk = (const float*)d_in[4];
    const float* Wv = (const float*)d_in[5];
    const float* bv = (const float*)d_in[6];
    const float* Wo = (const float*)d_in[7];
    const float* bo = (const float*)d_in[8];
    float* out = (float*)d_out;

    char* ws = (char*)d_ws;
    size_t off = 0;
    auto alloc = [&](size_t bytes) {
        void* p = ws + off;
        off += (bytes + 255) & ~(size_t)255;
        return p;
    };
    __bf16* xb    = (__bf16*)alloc((size_t)MTOK * DMODEL * 2);   // 12.6 MB (reused as ctx)
    __bf16* wtqkv = (__bf16*)alloc((size_t)NQKV * DMODEL * 2);   // 3.5 MB
    __bf16* wto   = (__bf16*)alloc((size_t)DMODEL * DMODEL * 2); // 1.2 MB
    float*  bqkv  = (float*)alloc((size_t)NQKV * 4);
    __bf16* qfb   = (__bf16*)alloc((size_t)MTOK * DMODEL * 2);   // 12.6 MB frag-linear Q
    __bf16* kfb   = (__bf16*)alloc((size_t)MTOK * DMODEL * 2);   // 12.6 MB frag-linear K
    __bf16* vfb   = (__bf16*)alloc((size_t)MTOK * DMODEL * 2);   // 12.6 MB frag-linear V
    if (off > ws_size) return;  // workspace too small -> visible failure
    __bf16* ctx = xb;  // xb dead after QKV GEMM

    k_prep<<<dim3(8457), dim3(256), 0, stream>>>(x, xb, Wq, Wk, Wv, Wo, wtqkv, wto,
                                                 bq, bk, bv, bqkv);
    k_gemm<__bf16, true, 128><<<dim3(64, 18), dim3(256), 0, stream>>>(
        xb, wtqkv, bqkv, (__bf16*)nullptr, NQKV, qfb, kfb, vfb);
    k_attn<<<dim3(3072), dim3(256), 0, stream>>>(qfb, kfb, vfb, ctx);
    k_gemm<float, false, 64><<<dim3(64, 12), dim3(256), 0, stream>>>(
        ctx, wto, bo, out, DMODEL, nullptr, nullptr, nullptr);
}